// Round 2
// baseline (2871.295 us; speedup 1.0000x reference)
//
#include <hip/hip_runtime.h>
#include <hip/hip_bf16.h>

#define NTOT 16384
#define NBAG 64
#define NMC  4
#define RFD  512
#define D0   1024
#define D1   512
#define D2   256
#define NATT 4
#define DATT 32
#define F1   1024   // 2*RF

static __device__ __forceinline__ unsigned short f2bf(float x){
  unsigned int u = __float_as_uint(x);
  u += 0x7fffu + ((u >> 16) & 1u);
  return (unsigned short)(u >> 16);
}
static __device__ __forceinline__ float bf2f(unsigned short h){
  return __uint_as_float(((unsigned int)h) << 16);
}

// ---- shared epilogue: rf features (cos||sin)*scale -> LayerNorm -> bf16 store
// acc[i][u][j] holds z for row (rg*4+i), col (u*128+cg*4+j).
// Trick: sum(f^2) over 1024 features = scale^2 * sum(cos^2+sin^2) = 1 exactly,
// so var = 1/1024 - mu^2; only the row sum is needed.
static __device__ __forceinline__ void rf_ln_store(float acc[4][4][4],
    unsigned short* phi, int m, int n0, int rg, int cg){
  const float scale = 0.044194173824159216f;  // 1/sqrt(512)
  float rowsum[4];
  #pragma unroll
  for (int i=0;i<4;i++){
    float s = 0.f;
    #pragma unroll
    for (int u=0;u<4;u++){
      #pragma unroll
      for (int j=0;j<4;j++){
        float sn, cs;
        __sincosf(acc[i][u][j], &sn, &cs);
        s += sn + cs;
      }
    }
    rowsum[i] = s;
  }
  // reduce over the 32 lanes (cg) that share each row group; rg groups are
  // lane ranges [0..31] / [32..63] within a wave, so xor masks <32 stay inside.
  #pragma unroll
  for (int off=1; off<32; off<<=1){
    #pragma unroll
    for (int i=0;i<4;i++) rowsum[i] += __shfl_xor(rowsum[i], off);
  }
  float mu[4], rs[4];
  #pragma unroll
  for (int i=0;i<4;i++){
    float muv = rowsum[i] * (scale / 1024.0f);
    float var = (1.0f/1024.0f) - muv*muv;
    rs[i] = 1.0f / sqrtf(var + 1e-5f);
    mu[i] = muv;
  }
  #pragma unroll
  for (int i=0;i<4;i++){
    size_t base = ((size_t)m*NTOT + (size_t)(n0 + rg*4 + i)) * (size_t)F1;
    #pragma unroll
    for (int u=0;u<4;u++){
      int c = u*128 + cg*4;
      float sn[4], cs[4];
      #pragma unroll
      for (int j=0;j<4;j++) __sincosf(acc[i][u][j], &sn[j], &cs[j]);
      ushort4 hc, hs;
      hc.x = f2bf((cs[0]*scale - mu[i]) * rs[i]);
      hc.y = f2bf((cs[1]*scale - mu[i]) * rs[i]);
      hc.z = f2bf((cs[2]*scale - mu[i]) * rs[i]);
      hc.w = f2bf((cs[3]*scale - mu[i]) * rs[i]);
      hs.x = f2bf((sn[0]*scale - mu[i]) * rs[i]);
      hs.y = f2bf((sn[1]*scale - mu[i]) * rs[i]);
      hs.z = f2bf((sn[2]*scale - mu[i]) * rs[i]);
      hs.w = f2bf((sn[3]*scale - mu[i]) * rs[i]);
      *(ushort4*)&phi[base + c]        = hc;
      *(ushort4*)&phi[base + RFD + c]  = hs;
    }
  }
}

// ---- K1: z1 = X @ Omega1[m]  (K=1024, out 512 cols)  -> rf/LN -> phi bf16
__global__ __launch_bounds__(256) void k_phi1(const float* __restrict__ X,
    const float* __restrict__ Om1, unsigned short* __restrict__ phi){
  const int m  = blockIdx.y;
  const int n0 = blockIdx.x * 32;
  const int t  = threadIdx.x;
  const int rg = t >> 5, cg = t & 31;
  __shared__ __align__(16) float As[16][36];
  __shared__ __align__(16) float Bs[16][512];
  float acc[4][4][4];
  for (int i=0;i<4;i++)
    for (int u=0;u<4;u++)
      for (int j=0;j<4;j++) acc[i][u][j]=0.f;
  const float* Bsrc = Om1 + (size_t)m * D0 * RFD;
  const int an = t >> 4, ak = t & 15;
  for (int k0 = 0; k0 < D0; k0 += 16){
    As[ak][an]    = X[(size_t)(n0+an)*D0    + k0 + ak];
    As[ak][an+16] = X[(size_t)(n0+an+16)*D0 + k0 + ak];
    #pragma unroll
    for (int r=0;r<8;r++){
      int flat4 = r*256 + t;
      int row = flat4 >> 7, c4 = flat4 & 127;
      *(float4*)&Bs[row][c4*4] = *(const float4*)&Bsrc[(size_t)(k0+row)*RFD + c4*4];
    }
    __syncthreads();
    #pragma unroll
    for (int kk=0;kk<16;kk++){
      float4 a = *(const float4*)&As[kk][rg*4];
      float aa[4] = {a.x,a.y,a.z,a.w};
      #pragma unroll
      for (int u=0;u<4;u++){
        float4 b = *(const float4*)&Bs[kk][u*128 + cg*4];
        float bb[4] = {b.x,b.y,b.z,b.w};
        #pragma unroll
        for (int i=0;i<4;i++){
          #pragma unroll
          for (int j=0;j<4;j++) acc[i][u][j] = fmaf(aa[i], bb[j], acc[i][u][j]);
        }
      }
    }
    __syncthreads();
  }
  rf_ln_store(acc, phi, m, n0, rg, cg);
}

// ---- K2: h1 = phi1@W1 + b1 (LDS, bf16) ; z2 = h1 @ Omega2[m] ; rf/LN -> phi (in place)
__global__ __launch_bounds__(256) void k_phi2(unsigned short* phi,
    const float* __restrict__ W1, const float* __restrict__ b1,
    const float* __restrict__ Om2){
  const int m  = blockIdx.y;
  const int n0 = blockIdx.x * 32;
  const int t  = threadIdx.x;
  const int rg = t >> 5, cg = t & 31;
  __shared__ __align__(16) float As[8][36];
  __shared__ __align__(16) float Bs[8][512];
  __shared__ __align__(16) unsigned short hsT[512][40];
  float acc[4][4][4];
  for (int i=0;i<4;i++)
    for (int u=0;u<4;u++)
      for (int j=0;j<4;j++) acc[i][u][j]=0.f;
  // GEMM1: K = 1024 over phi features, B = W1
  for (int k0=0;k0<F1;k0+=8){
    if (t < 128){
      int an = t >> 2, af = t & 3;
      unsigned int v = *(const unsigned int*)&phi[((size_t)m*NTOT + n0 + an)*F1 + k0 + af*2];
      As[af*2][an]   = bf2f((unsigned short)(v & 0xffffu));
      As[af*2+1][an] = bf2f((unsigned short)(v >> 16));
    }
    #pragma unroll
    for (int r=0;r<4;r++){
      int flat4 = r*256 + t;
      int row = flat4 >> 7, c4 = flat4 & 127;
      *(float4*)&Bs[row][c4*4] = *(const float4*)&W1[(size_t)(k0+row)*D1 + c4*4];
    }
    __syncthreads();
    #pragma unroll
    for (int kk=0;kk<8;kk++){
      float4 a = *(const float4*)&As[kk][rg*4];
      float aa[4] = {a.x,a.y,a.z,a.w};
      #pragma unroll
      for (int u=0;u<4;u++){
        float4 b = *(const float4*)&Bs[kk][u*128 + cg*4];
        float bb[4] = {b.x,b.y,b.z,b.w};
        #pragma unroll
        for (int i=0;i<4;i++){
          #pragma unroll
          for (int j=0;j<4;j++) acc[i][u][j] = fmaf(aa[i], bb[j], acc[i][u][j]);
        }
      }
    }
    __syncthreads();
  }
  // h -> hsT (transposed, bf16), +b1
  #pragma unroll
  for (int u=0;u<4;u++){
    #pragma unroll
    for (int j=0;j<4;j++){
      int c = u*128 + cg*4 + j;
      float bv = b1[c];
      #pragma unroll
      for (int i=0;i<4;i++) hsT[c][rg*4+i] = f2bf(acc[i][u][j] + bv);
    }
  }
  __syncthreads();
  // GEMM2: K = 512 over h, B = Omega2[m]
  for (int i=0;i<4;i++)
    for (int u=0;u<4;u++)
      for (int j=0;j<4;j++) acc[i][u][j]=0.f;
  const float* B2 = Om2 + (size_t)m * D1 * RFD;
  for (int k0=0;k0<D1;k0+=8){
    #pragma unroll
    for (int r=0;r<4;r++){
      int flat4 = r*256 + t;
      int row = flat4 >> 7, c4 = flat4 & 127;
      *(float4*)&Bs[row][c4*4] = *(const float4*)&B2[(size_t)(k0+row)*RFD + c4*4];
    }
    __syncthreads();
    #pragma unroll
    for (int kk=0;kk<8;kk++){
      ushort4 av = *(const ushort4*)&hsT[k0+kk][rg*4];
      float aa[4] = {bf2f(av.x), bf2f(av.y), bf2f(av.z), bf2f(av.w)};
      #pragma unroll
      for (int u=0;u<4;u++){
        float4 b = *(const float4*)&Bs[kk][u*128 + cg*4];
        float bb[4] = {b.x,b.y,b.z,b.w};
        #pragma unroll
        for (int i=0;i<4;i++){
          #pragma unroll
          for (int j=0;j<4;j++) acc[i][u][j] = fmaf(aa[i], bb[j], acc[i][u][j]);
        }
      }
    }
    __syncthreads();
  }
  rf_ln_store(acc, phi, m, n0, rg, cg);
}

// ---- K3: emb = phi2 @ W2 + b2  (K=1024, out 256 cols, f32)
__global__ __launch_bounds__(256) void k_emb(const unsigned short* __restrict__ phi,
    const float* __restrict__ W2, const float* __restrict__ b2, float* __restrict__ emb){
  const int m  = blockIdx.y;
  const int n0 = blockIdx.x * 32;
  const int t  = threadIdx.x;
  const int rg = t >> 5, cg = t & 31;
  __shared__ __align__(16) float As[16][36];
  __shared__ __align__(16) float Bs[16][256];
  float acc[4][2][4];
  for (int i=0;i<4;i++)
    for (int u=0;u<2;u++)
      for (int j=0;j<4;j++) acc[i][u][j]=0.f;
  const int an = t >> 3, af = t & 7;
  const size_t arow = ((size_t)m*NTOT + n0 + an) * F1;
  for (int k0=0;k0<F1;k0+=16){
    unsigned int v = *(const unsigned int*)&phi[arow + k0 + af*2];
    As[af*2][an]   = bf2f((unsigned short)(v & 0xffffu));
    As[af*2+1][an] = bf2f((unsigned short)(v >> 16));
    #pragma unroll
    for (int r=0;r<4;r++){
      int flat4 = r*256 + t;
      int row = flat4 >> 6, c4 = flat4 & 63;
      *(float4*)&Bs[row][c4*4] = *(const float4*)&W2[(size_t)(k0+row)*D2 + c4*4];
    }
    __syncthreads();
    #pragma unroll
    for (int kk=0;kk<16;kk++){
      float4 a = *(const float4*)&As[kk][rg*4];
      float aa[4] = {a.x,a.y,a.z,a.w};
      #pragma unroll
      for (int u=0;u<2;u++){
        float4 b = *(const float4*)&Bs[kk][u*128 + cg*4];
        float bb[4] = {b.x,b.y,b.z,b.w};
        #pragma unroll
        for (int i=0;i<4;i++){
          #pragma unroll
          for (int j=0;j<4;j++) acc[i][u][j] = fmaf(aa[i], bb[j], acc[i][u][j]);
        }
      }
    }
    __syncthreads();
  }
  #pragma unroll
  for (int i=0;i<4;i++){
    size_t base = ((size_t)m*NTOT + n0 + rg*4 + i) * D2;
    #pragma unroll
    for (int u=0;u<2;u++){
      int c = u*128 + cg*4;
      float4 o;
      o.x = acc[i][u][0] + b2[c+0];
      o.y = acc[i][u][1] + b2[c+1];
      o.z = acc[i][u][2] + b2[c+2];
      o.w = acc[i][u][3] + b2[c+3];
      *(float4*)&emb[base + c] = o;
    }
  }
}

// ---- K4: p[m][n][k] = exp((emb[m,n,:]·Ws[:,k] + bs[k]) / 16)
__global__ __launch_bounds__(256) void k_scores(const float* __restrict__ emb,
    const float* __restrict__ Wsm, const float* __restrict__ bsv, float* __restrict__ p){
  const int m = blockIdx.y;
  const int n = blockIdx.x * 256 + threadIdx.x;
  __shared__ float Wss[D2*NATT];
  ((float4*)Wss)[threadIdx.x] = ((const float4*)Wsm)[threadIdx.x];
  __syncthreads();
  const float4* er = (const float4*)(emb + ((size_t)m*NTOT + n) * D2);
  float d0=0.f,d1=0.f,d2=0.f,d3=0.f;
  for (int d4=0; d4<64; d4++){
    float4 e = er[d4];
    const float* w = &Wss[d4*16];
    d0 += e.x*w[0] + e.y*w[4] + e.z*w[8]  + e.w*w[12];
    d1 += e.x*w[1] + e.y*w[5] + e.z*w[9]  + e.w*w[13];
    d2 += e.x*w[2] + e.y*w[6] + e.z*w[10] + e.w*w[14];
    d3 += e.x*w[3] + e.y*w[7] + e.z*w[11] + e.w*w[15];
  }
  float4 o;
  o.x = expf((d0 + bsv[0]) * 0.0625f);
  o.y = expf((d1 + bsv[1]) * 0.0625f);
  o.z = expf((d2 + bsv[2]) * 0.0625f);
  o.w = expf((d3 + bsv[3]) * 0.0625f);
  ((float4*)p)[(size_t)m*NTOT + n] = o;
}

// ---- K5: bag start offsets (X_idx is sorted)
__global__ void k_starts(const int* __restrict__ idx, int* __restrict__ starts){
  int t = threadIdx.x;
  if (t <= NBAG){
    int lo = 0, hi = NTOT;
    while (lo < hi){ int mid = (lo + hi) >> 1; if (idx[mid] < t) lo = mid + 1; else hi = mid; }
    starts[t] = lo;
  }
}

// ---- K6: emb_new = relu(emb @ Wm + bm) -> bf16  (K=256, out 128 cols)
__global__ __launch_bounds__(256) void k_embnew(const float* __restrict__ emb,
    const float* __restrict__ Wm, const float* __restrict__ bm, unsigned short* __restrict__ en){
  const int m  = blockIdx.y;
  const int n0 = blockIdx.x * 32;
  const int t  = threadIdx.x;
  const int rg = t >> 5, cg = t & 31;
  __shared__ __align__(16) float As[32][36];
  __shared__ __align__(16) float Bs[32][128];
  float acc[4][4];
  for (int i=0;i<4;i++)
    for (int j=0;j<4;j++) acc[i][j]=0.f;
  const int an = t >> 3, ak = t & 7;
  for (int k0=0;k0<D2;k0+=32){
    float4 v = *(const float4*)&emb[((size_t)m*NTOT + n0 + an)*D2 + k0 + ak*4];
    As[ak*4+0][an]=v.x; As[ak*4+1][an]=v.y; As[ak*4+2][an]=v.z; As[ak*4+3][an]=v.w;
    #pragma unroll
    for (int r=0;r<4;r++){
      int flat4 = r*256 + t;
      int row = flat4 >> 5, c4 = flat4 & 31;
      *(float4*)&Bs[row][c4*4] = *(const float4*)&Wm[(size_t)(k0+row)*128 + c4*4];
    }
    __syncthreads();
    #pragma unroll
    for (int kk=0;kk<32;kk++){
      float4 a = *(const float4*)&As[kk][rg*4];
      float aa[4] = {a.x,a.y,a.z,a.w};
      float4 b = *(const float4*)&Bs[kk][cg*4];
      float bb[4] = {b.x,b.y,b.z,b.w};
      #pragma unroll
      for (int i=0;i<4;i++){
        #pragma unroll
        for (int j=0;j<4;j++) acc[i][j] = fmaf(aa[i], bb[j], acc[i][j]);
      }
    }
    __syncthreads();
  }
  #pragma unroll
  for (int i=0;i<4;i++){
    ushort4 h;
    h.x = f2bf(fmaxf(acc[i][0] + bm[cg*4+0], 0.f));
    h.y = f2bf(fmaxf(acc[i][1] + bm[cg*4+1], 0.f));
    h.z = f2bf(fmaxf(acc[i][2] + bm[cg*4+2], 0.f));
    h.w = f2bf(fmaxf(acc[i][3] + bm[cg*4+3], 0.f));
    *(ushort4*)&en[((size_t)m*NTOT + n0 + rg*4 + i)*128 + cg*4] = h;
  }
}

// ---- K7: per (bag,m): seg = sum p; out[e] = sum_n en * p[k]/seg[k]
__global__ __launch_bounds__(256) void k_pool(const unsigned short* __restrict__ en,
    const float* __restrict__ p, const int* __restrict__ starts, float* __restrict__ out){
  const int b = blockIdx.x, m = blockIdx.y;
  const int t = threadIdx.x;
  const int s0 = starts[b], s1 = starts[b+1];
  float sp0=0.f,sp1=0.f,sp2=0.f,sp3=0.f;
  for (int n = s0 + t; n < s1; n += 256){
    float4 pv = ((const float4*)p)[(size_t)m*NTOT + n];
    sp0 += pv.x; sp1 += pv.y; sp2 += pv.z; sp3 += pv.w;
  }
  #pragma unroll
  for (int off=1; off<64; off<<=1){
    sp0 += __shfl_xor(sp0, off); sp1 += __shfl_xor(sp1, off);
    sp2 += __shfl_xor(sp2, off); sp3 += __shfl_xor(sp3, off);
  }
  __shared__ float wred[4][4];
  __shared__ float winv[4];
  if ((t & 63) == 0){ wred[t>>6][0]=sp0; wred[t>>6][1]=sp1; wred[t>>6][2]=sp2; wred[t>>6][3]=sp3; }
  __syncthreads();
  if (t < 4){
    float s = wred[0][t] + wred[1][t] + wred[2][t] + wred[3][t];
    winv[t] = (s > 0.f) ? 1.0f / s : 0.f;
  }
  __syncthreads();
  const int e = t & 127, half = t >> 7;
  const int k = e >> 5;
  float accv = 0.f;
  for (int n = s0 + half; n < s1; n += 2){
    float w = p[((size_t)m*NTOT + n)*4 + k];
    float v = bf2f(en[((size_t)m*NTOT + n)*128 + e]);
    accv = fmaf(v, w, accv);
  }
  accv *= winv[k];
  __shared__ float ac2[2][128];
  ac2[half][e] = accv;
  __syncthreads();
  if (t < 128) out[((size_t)b*NMC + m)*128 + t] = ac2[0][t] + ac2[1][t];
}

extern "C" void kernel_launch(void* const* d_in, const int* in_sizes, int n_in,
                              void* d_out, int out_size, void* d_ws, size_t ws_size,
                              hipStream_t stream) {
  const float* X    = (const float*)d_in[0];
  const int*   Xidx = (const int*)  d_in[1];
  const float* Om1  = (const float*)d_in[2];
  const float* Om2  = (const float*)d_in[3];
  const float* W1   = (const float*)d_in[4];
  const float* b1   = (const float*)d_in[5];
  const float* W2   = (const float*)d_in[6];
  const float* b2   = (const float*)d_in[7];
  const float* Wsm  = (const float*)d_in[8];
  const float* bsv  = (const float*)d_in[9];
  const float* Wm   = (const float*)d_in[10];
  const float* bm   = (const float*)d_in[11];
  float* out = (float*)d_out;

  char* ws = (char*)d_ws;
  unsigned short* phi = (unsigned short*)ws;                       // 128 MB bf16 [m][n][1024]
  float* emb          = (float*)(ws + 134217728ull);               // 64 MB f32 [m][n][256]
  unsigned short* en  = (unsigned short*)(ws + 201326592ull);      // 16 MB bf16 [m][n][128]
  float* p            = (float*)(ws + 218103808ull);               // 1 MB f32 [m][n][4]
  int* starts         = (int*)(ws + 219152384ull);                 // 260 B

  k_phi1  <<<dim3(NTOT/32, NMC), 256, 0, stream>>>(X, Om1, phi);
  k_phi2  <<<dim3(NTOT/32, NMC), 256, 0, stream>>>(phi, W1, b1, Om2);
  k_emb   <<<dim3(NTOT/32, NMC), 256, 0, stream>>>(phi, W2, b2, emb);
  k_scores<<<dim3(NTOT/256, NMC), 256, 0, stream>>>(emb, Wsm, bsv, p);
  k_embnew<<<dim3(NTOT/32, NMC), 256, 0, stream>>>(emb, Wm, bm, en);
  k_starts<<<1, 128, 0, stream>>>(Xidx, starts);
  k_pool  <<<dim3(NBAG, NMC), 256, 0, stream>>>(en, p, starts, out);
}

// Round 3
// 828.082 us; speedup vs baseline: 3.4674x; 3.4674x over previous
//
#include <hip/hip_runtime.h>

#define NTOT 16384
#define NBAG 64
#define NMC  4

typedef __attribute__((ext_vector_type(8))) short bf8_t;       // 8 x bf16 payload
typedef __attribute__((ext_vector_type(4))) float f32x4;
typedef __attribute__((ext_vector_type(8))) unsigned short u16x8;

#define GLD16(g, l) __builtin_amdgcn_global_load_lds( \
    (const __attribute__((address_space(1))) void*)(g), \
    (__attribute__((address_space(3))) void*)(l), 16, 0, 0)

static __device__ __forceinline__ unsigned short f2bf(float x){
  unsigned int u = __float_as_uint(x);
  u += 0x7fffu + ((u >> 16) & 1u);
  return (unsigned short)(u >> 16);
}
static __device__ __forceinline__ float bf2f(unsigned short h){
  return __uint_as_float(((unsigned int)h) << 16);
}
static __device__ __forceinline__ f32x4 mfma16(bf8_t a, bf8_t b, f32x4 c){
  return __builtin_amdgcn_mfma_f32_16x16x32_bf16(a, b, c, 0, 0, 0);
}

// ---------- conversion / repack kernels ----------
__global__ __launch_bounds__(256) void k_cvt(const float* __restrict__ src,
    unsigned short* __restrict__ dst, int n8){
  for (int i = blockIdx.x*256 + threadIdx.x; i < n8; i += gridDim.x*256){
    float4 v0 = ((const float4*)src)[i*2];
    float4 v1 = ((const float4*)src)[i*2+1];
    u16x8 o;
    o[0]=f2bf(v0.x); o[1]=f2bf(v0.y); o[2]=f2bf(v0.z); o[3]=f2bf(v0.w);
    o[4]=f2bf(v1.x); o[5]=f2bf(v1.y); o[6]=f2bf(v1.z); o[7]=f2bf(v1.w);
    ((u16x8*)dst)[i] = o;
  }
}

// dst[kg][c][i] = bf16(src[(8kg+i)*N + c]);  batched over blockIdx.y
__global__ __launch_bounds__(256) void k_pack8(const float* __restrict__ src,
    unsigned short* __restrict__ dst, int K, int N){
  const size_t base = (size_t)blockIdx.y * K * N;
  int idx = blockIdx.x*256 + threadIdx.x;     // idx = kg*N + c
  int kg = idx / N, c = idx % N;
  const float* s = src + base + (size_t)(kg*8)*N + c;
  u16x8 o;
  #pragma unroll
  for (int i=0;i<8;i++) o[i] = f2bf(s[(size_t)i*N]);
  ((u16x8*)(dst + base))[idx] = o;
}

// ---------- shared rf-features + LayerNorm epilogue ----------
// acc[rt][ct][j] = z for row (n0 + row0 + rt*16 + 4*(l>>4)+j), col (colhalf*256 + ct*16 + (l&15))
// sum(f^2) over 1024 features = 1 exactly (cos^2+sin^2), so var = 1/1024 - mu^2.
template<int RT>
static __device__ __forceinline__ void rf_ln_store(f32x4 (&acc)[RT][16],
    unsigned short* __restrict__ phiM, float* rowp, int row0,
    int n0, int colhalf, int l){
  const float scale = 0.044194173824159216f;  // 1/sqrt(512)
  const int g = l >> 4, li = l & 15;
  float part[RT][4];
  #pragma unroll
  for (int rt=0; rt<RT; rt++){
    #pragma unroll
    for (int j=0;j<4;j++){
      float s = 0.f;
      #pragma unroll
      for (int ct=0; ct<16; ct++){
        float sn, cs; __sincosf(acc[rt][ct][j], &sn, &cs);
        s += sn + cs;
      }
      #pragma unroll
      for (int off=1; off<16; off<<=1) s += __shfl_xor(s, off);
      part[rt][j] = s;
    }
  }
  if (li == 0){
    #pragma unroll
    for (int rt=0; rt<RT; rt++)
      #pragma unroll
      for (int j=0;j<4;j++)
        rowp[(row0 + rt*16 + 4*g + j)*2 + colhalf] = part[rt][j];
  }
  __syncthreads();
  #pragma unroll
  for (int rt=0; rt<RT; rt++){
    #pragma unroll
    for (int j=0;j<4;j++){
      int rb = row0 + rt*16 + 4*g + j;
      float tot = rowp[rb*2+0] + rowp[rb*2+1];
      float mu = tot * (scale / 1024.0f);
      float rs = 1.0f / sqrtf((1.0f/1024.0f) - mu*mu + 1e-5f);
      size_t base = (size_t)(n0 + rb) * 1024;
      #pragma unroll
      for (int ct=0; ct<16; ct++){
        int c = colhalf*256 + ct*16 + li;
        float sn, cs; __sincosf(acc[rt][ct][j], &sn, &cs);
        phiM[base + c]       = f2bf((cs*scale - mu)*rs);
        phiM[base + 512 + c] = f2bf((sn*scale - mu)*rs);
      }
    }
  }
}

// ---------- K1: z1 = Xb @ Om1f[m] -> rf/LN -> phi ----------
// block: 64 rows x 512 cols; wave w: rows (w>>1)*32..+31, cols (w&1)*256..+255
__global__ __launch_bounds__(256) void k_phi1(const unsigned short* __restrict__ Xb,
    const unsigned short* __restrict__ Om1f, unsigned short* __restrict__ phi){
  const int m = blockIdx.y, n0 = blockIdx.x*64;
  const int t = threadIdx.x, w = t>>6, l = t&63;
  const int g = l>>4, li = l&15;
  const int wrow = (w>>1)*32, ch = w&1;
  const int wvb = (t & ~63);
  __shared__ unsigned short Bs[16384];   // [4 kg][512 col][8] = 32KB
  __shared__ float rowp[128];            // [64][2]
  f32x4 acc[2][16];
  const f32x4 z4 = {0.f,0.f,0.f,0.f};
  #pragma unroll
  for (int rt=0;rt<2;rt++)
    #pragma unroll
    for (int ct=0;ct<16;ct++) acc[rt][ct] = z4;
  const unsigned short* bsrc = Om1f + (size_t)m*524288;
  const unsigned short* ar0 = Xb + (size_t)(n0 + wrow + li)*1024 + g*8;
  const unsigned short* ar1 = ar0 + 16*1024;
  for (int ks=0; ks<32; ks++){
    __syncthreads();
    #pragma unroll
    for (int it=0; it<8; it++)
      GLD16(bsrc + (size_t)ks*16384 + it*2048 + t*8, Bs + it*2048 + wvb*8);
    bf8_t a0 = *(const bf8_t*)(ar0 + ks*32);
    bf8_t a1 = *(const bf8_t*)(ar1 + ks*32);
    asm volatile("s_waitcnt vmcnt(0)" ::: "memory");
    __syncthreads();
    #pragma unroll
    for (int ct=0; ct<16; ct++){
      bf8_t b = *(const bf8_t*)(Bs + g*4096 + (ch*256 + ct*16 + li)*8);
      acc[0][ct] = mfma16(a0, b, acc[0][ct]);
      acc[1][ct] = mfma16(a1, b, acc[1][ct]);
    }
  }
  rf_ln_store<2>(acc, phi + (size_t)m*NTOT*1024, rowp, wrow, n0, ch, l);
}

// ---------- K2: h = phi1@W1f + b1 (LDS bf16) ; z2 = h @ Om2f[m] -> rf/LN -> phi in place ----------
// block: 32 rows; wave w: rows (w>>1)*16..+15, cols (w&1)*256..+255
__global__ __launch_bounds__(256) void k_phi2(unsigned short* __restrict__ phi,
    const unsigned short* __restrict__ W1f, const float* __restrict__ b1,
    const unsigned short* __restrict__ Om2f){
  const int m = blockIdx.y, n0 = blockIdx.x*32;
  const int t = threadIdx.x, w = t>>6, l = t&63;
  const int g = l>>4, li = l&15;
  const int wrow = (w>>1)*16, ch = w&1;
  const int wvb = (t & ~63);
  __shared__ unsigned short Bs[16384];   // 32KB staging
  __shared__ unsigned short hs[32*520];  // padded: row stride 1040B
  __shared__ float rowp[64];             // [32][2]
  f32x4 acc[1][16];
  const f32x4 z4 = {0.f,0.f,0.f,0.f};
  #pragma unroll
  for (int ct=0;ct<16;ct++) acc[0][ct] = z4;
  const unsigned short* arow = phi + ((size_t)m*NTOT + n0 + wrow + li)*1024 + g*8;
  // stage 1: K=1024 over phi features, B = W1f
  for (int ks=0; ks<32; ks++){
    __syncthreads();
    #pragma unroll
    for (int it=0; it<8; it++)
      GLD16(W1f + (size_t)ks*16384 + it*2048 + t*8, Bs + it*2048 + wvb*8);
    bf8_t a = *(const bf8_t*)(arow + ks*32);
    asm volatile("s_waitcnt vmcnt(0)" ::: "memory");
    __syncthreads();
    #pragma unroll
    for (int ct=0; ct<16; ct++){
      bf8_t b = *(const bf8_t*)(Bs + g*4096 + (ch*256 + ct*16 + li)*8);
      acc[0][ct] = mfma16(a, b, acc[0][ct]);
    }
  }
  // h -> LDS (bf16, +b1)
  #pragma unroll
  for (int ct=0; ct<16; ct++){
    int c = ch*256 + ct*16 + li;
    float bv = b1[c];
    #pragma unroll
    for (int j=0;j<4;j++){
      int row = wrow + 4*g + j;
      hs[row*520 + c] = f2bf(acc[0][ct][j] + bv);
    }
  }
  // stage 2: K=512 over h, B = Om2f[m]
  #pragma unroll
  for (int ct=0;ct<16;ct++) acc[0][ct] = z4;
  const unsigned short* b2src = Om2f + (size_t)m*262144;
  for (int ks=0; ks<16; ks++){
    __syncthreads();
    #pragma unroll
    for (int it=0; it<8; it++)
      GLD16(b2src + (size_t)ks*16384 + it*2048 + t*8, Bs + it*2048 + wvb*8);
    bf8_t a = *(const bf8_t*)(&hs[(wrow + li)*520 + ks*32 + g*8]);
    asm volatile("s_waitcnt vmcnt(0)" ::: "memory");
    __syncthreads();
    #pragma unroll
    for (int ct=0; ct<16; ct++){
      bf8_t b = *(const bf8_t*)(Bs + g*4096 + (ch*256 + ct*16 + li)*8);
      acc[0][ct] = mfma16(a, b, acc[0][ct]);
    }
  }
  rf_ln_store<1>(acc, phi + (size_t)m*NTOT*1024, rowp, wrow, n0, ch, l);
}

// ---------- K3: emb = phi2 @ W2f + b2 -> bf16 ----------
// block: 64 rows x 256 cols; wave w: rows w*16, all 256 cols
__global__ __launch_bounds__(256) void k_emb(const unsigned short* __restrict__ phi,
    const unsigned short* __restrict__ W2f, const float* __restrict__ b2,
    unsigned short* __restrict__ emb){
  const int m = blockIdx.y, n0 = blockIdx.x*64;
  const int t = threadIdx.x, w = t>>6, l = t&63;
  const int g = l>>4, li = l&15;
  const int wvb = (t & ~63);
  __shared__ unsigned short Bs[8192];    // [4][256][8] = 16KB
  f32x4 acc[16];
  const f32x4 z4 = {0.f,0.f,0.f,0.f};
  #pragma unroll
  for (int ct=0;ct<16;ct++) acc[ct] = z4;
  const unsigned short* arow = phi + ((size_t)m*NTOT + n0 + w*16 + li)*1024 + g*8;
  for (int ks=0; ks<32; ks++){
    __syncthreads();
    #pragma unroll
    for (int it=0; it<4; it++)
      GLD16(W2f + (size_t)ks*8192 + it*2048 + t*8, Bs + it*2048 + wvb*8);
    bf8_t a = *(const bf8_t*)(arow + ks*32);
    asm volatile("s_waitcnt vmcnt(0)" ::: "memory");
    __syncthreads();
    #pragma unroll
    for (int ct=0; ct<16; ct++){
      bf8_t b = *(const bf8_t*)(Bs + g*2048 + (ct*16 + li)*8);
      acc[ct] = mfma16(a, b, acc[ct]);
    }
  }
  #pragma unroll
  for (int ct=0; ct<16; ct++){
    int c = ct*16 + li;
    float bv = b2[c];
    #pragma unroll
    for (int j=0;j<4;j++)
      emb[((size_t)m*NTOT + n0 + w*16 + 4*g + j)*256 + c] = f2bf(acc[ct][j] + bv);
  }
}

// ---------- K4: scores -> p = exp((emb.Ws + bs)/16) ----------
__global__ __launch_bounds__(256) void k_scores(const unsigned short* __restrict__ emb,
    const float* __restrict__ Wsm, const float* __restrict__ bsv, float* __restrict__ p){
  const int m = blockIdx.y;
  const int n = blockIdx.x*256 + threadIdx.x;
  __shared__ float Wss[1024];
  ((float4*)Wss)[threadIdx.x] = ((const float4*)Wsm)[threadIdx.x];
  __syncthreads();
  const u16x8* er = (const u16x8*)(emb + ((size_t)m*NTOT + n)*256);
  float a0=0.f,a1=0.f,a2=0.f,a3=0.f;
  for (int d8=0; d8<32; d8++){
    u16x8 e = er[d8];
    #pragma unroll
    for (int i=0;i<8;i++){
      float ev = bf2f(e[i]);
      const float* wv = &Wss[(d8*8+i)*4];
      a0 += ev*wv[0]; a1 += ev*wv[1]; a2 += ev*wv[2]; a3 += ev*wv[3];
    }
  }
  float4 o;
  o.x = expf((a0 + bsv[0]) * 0.0625f);
  o.y = expf((a1 + bsv[1]) * 0.0625f);
  o.z = expf((a2 + bsv[2]) * 0.0625f);
  o.w = expf((a3 + bsv[3]) * 0.0625f);
  ((float4*)p)[(size_t)m*NTOT + n] = o;
}

// ---------- K5: bag start offsets ----------
__global__ void k_starts(const int* __restrict__ idx, int* __restrict__ starts){
  int t = threadIdx.x;
  if (t <= NBAG){
    int lo = 0, hi = NTOT;
    while (lo < hi){ int mid = (lo + hi) >> 1; if (idx[mid] < t) lo = mid + 1; else hi = mid; }
    starts[t] = lo;
  }
}

// ---------- K6: en = relu(emb @ Wmf + bm) -> bf16 ----------
__global__ __launch_bounds__(256) void k_embnew(const unsigned short* __restrict__ emb,
    const unsigned short* __restrict__ Wmf, const float* __restrict__ bm,
    unsigned short* __restrict__ en){
  const int m = blockIdx.y, n0 = blockIdx.x*64;
  const int t = threadIdx.x, w = t>>6, l = t&63;
  const int g = l>>4, li = l&15;
  const int wvb = (t & ~63);
  __shared__ unsigned short Bs[32768];   // full Wmf [32][128][8] = 64KB
  #pragma unroll
  for (int it=0; it<16; it++)
    GLD16(Wmf + it*2048 + t*8, Bs + it*2048 + wvb*8);
  asm volatile("s_waitcnt vmcnt(0)" ::: "memory");
  __syncthreads();
  f32x4 acc[8];
  const f32x4 z4 = {0.f,0.f,0.f,0.f};
  #pragma unroll
  for (int ct=0;ct<8;ct++) acc[ct] = z4;
  const unsigned short* arow = emb + ((size_t)m*NTOT + n0 + w*16 + li)*256 + g*8;
  #pragma unroll
  for (int ks=0; ks<8; ks++){
    bf8_t a = *(const bf8_t*)(arow + ks*32);
    #pragma unroll
    for (int ct=0; ct<8; ct++){
      bf8_t b = *(const bf8_t*)(Bs + (ks*4+g)*1024 + (ct*16 + li)*8);
      acc[ct] = mfma16(a, b, acc[ct]);
    }
  }
  #pragma unroll
  for (int ct=0; ct<8; ct++){
    int c = ct*16 + li;
    float bv = bm[c];
    #pragma unroll
    for (int j=0;j<4;j++)
      en[((size_t)m*NTOT + n0 + w*16 + 4*g + j)*128 + c] = f2bf(fmaxf(acc[ct][j] + bv, 0.f));
  }
}

// ---------- K7: per (bag,m): seg = sum p; out[e] = sum_n en * p[k]/seg[k] ----------
__global__ __launch_bounds__(256) void k_pool(const unsigned short* __restrict__ en,
    const float* __restrict__ p, const int* __restrict__ starts, float* __restrict__ out){
  const int b = blockIdx.x, m = blockIdx.y;
  const int t = threadIdx.x;
  const int s0 = starts[b], s1 = starts[b+1];
  float sp0=0.f,sp1=0.f,sp2=0.f,sp3=0.f;
  for (int n = s0 + t; n < s1; n += 256){
    float4 pv = ((const float4*)p)[(size_t)m*NTOT + n];
    sp0 += pv.x; sp1 += pv.y; sp2 += pv.z; sp3 += pv.w;
  }
  #pragma unroll
  for (int off=1; off<64; off<<=1){
    sp0 += __shfl_xor(sp0, off); sp1 += __shfl_xor(sp1, off);
    sp2 += __shfl_xor(sp2, off); sp3 += __shfl_xor(sp3, off);
  }
  __shared__ float wred[4][4];
  __shared__ float winv[4];
  if ((t & 63) == 0){ wred[t>>6][0]=sp0; wred[t>>6][1]=sp1; wred[t>>6][2]=sp2; wred[t>>6][3]=sp3; }
  __syncthreads();
  if (t < 4){
    float s = wred[0][t] + wred[1][t] + wred[2][t] + wred[3][t];
    winv[t] = (s > 0.f) ? 1.0f / s : 0.f;
  }
  __syncthreads();
  const int e = t & 127, half = t >> 7;
  const int k = e >> 5;
  float accv = 0.f;
  for (int n = s0 + half; n < s1; n += 2){
    float wq = p[((size_t)m*NTOT + n)*4 + k];
    float v = bf2f(en[((size_t)m*NTOT + n)*128 + e]);
    accv = fmaf(v, wq, accv);
  }
  accv *= winv[k];
  __shared__ float ac2[2][128];
  ac2[half][e] = accv;
  __syncthreads();
  if (t < 128) out[((size_t)b*NMC + m)*128 + t] = ac2[0][t] + ac2[1][t];
}

extern "C" void kernel_launch(void* const* d_in, const int* in_sizes, int n_in,
                              void* d_out, int out_size, void* d_ws, size_t ws_size,
                              hipStream_t stream) {
  const float* X    = (const float*)d_in[0];
  const int*   Xidx = (const int*)  d_in[1];
  const float* Om1  = (const float*)d_in[2];
  const float* Om2  = (const float*)d_in[3];
  const float* W1   = (const float*)d_in[4];
  const float* b1   = (const float*)d_in[5];
  const float* W2   = (const float*)d_in[6];
  const float* b2   = (const float*)d_in[7];
  const float* Wsm  = (const float*)d_in[8];
  const float* bsv  = (const float*)d_in[9];
  const float* Wm   = (const float*)d_in[10];
  const float* bm   = (const float*)d_in[11];
  float* out = (float*)d_out;

  char* ws = (char*)d_ws;
  unsigned short* phi  = (unsigned short*)(ws);                    // 128MB [m][n][1024]
  unsigned short* Xb   = (unsigned short*)(ws + 134217728ull);     // 32MB (dead after k_phi1)
  unsigned short* emb  = (unsigned short*)(ws + 134217728ull);     // 32MB (aliases Xb)
  unsigned short* en   = (unsigned short*)(ws + 167772160ull);     // 16MB
  float* p             = (float*)(ws + 184549376ull);              // 1MB
  int* starts          = (int*)(ws + 185597952ull);                // 1KB
  unsigned short* Om1f = (unsigned short*)(ws + 185598976ull);     // 4MB
  unsigned short* W1f  = (unsigned short*)(ws + 189793280ull);     // 1MB
  unsigned short* Om2f = (unsigned short*)(ws + 190841856ull);     // 2MB
  unsigned short* W2f  = (unsigned short*)(ws + 192939008ull);     // 0.5MB
  unsigned short* Wmf  = (unsigned short*)(ws + 193463296ull);     // 64KB

  k_cvt   <<<2048, 256, 0, stream>>>(X, Xb, NTOT*1024/8);
  k_pack8 <<<dim3(256,4), 256, 0, stream>>>(Om1, Om1f, 1024, 512);
  k_pack8 <<<dim3(256,1), 256, 0, stream>>>(W1,  W1f,  1024, 512);
  k_pack8 <<<dim3(128,4), 256, 0, stream>>>(Om2, Om2f, 512,  512);
  k_pack8 <<<dim3(128,1), 256, 0, stream>>>(W2,  W2f,  1024, 256);
  k_pack8 <<<dim3(16,1),  256, 0, stream>>>(Wm,  Wmf,  256,  128);
  k_phi1  <<<dim3(256,4), 256, 0, stream>>>(Xb, Om1f, phi);
  k_phi2  <<<dim3(512,4), 256, 0, stream>>>(phi, W1f, b1, Om2f);
  k_emb   <<<dim3(256,4), 256, 0, stream>>>(phi, W2f, b2, emb);
  k_scores<<<dim3(64,4),  256, 0, stream>>>(emb, Wsm, bsv, p);
  k_embnew<<<dim3(256,4), 256, 0, stream>>>(emb, Wmf, bm, en);
  k_starts<<<1, 128, 0, stream>>>(Xidx, starts);
  k_pool  <<<dim3(64,4),  256, 0, stream>>>(en, p, starts, out);
}

// Round 4
// 661.345 us; speedup vs baseline: 4.3416x; 1.2521x over previous
//
#include <hip/hip_runtime.h>

#define NTOT 16384
#define NBAG 64
#define NMC  4

typedef __attribute__((ext_vector_type(8))) short bf8_t;       // 8 x bf16 payload
typedef __attribute__((ext_vector_type(4))) float f32x4;
typedef __attribute__((ext_vector_type(8))) unsigned short u16x8;

#define GLD16(g, l) __builtin_amdgcn_global_load_lds( \
    (const __attribute__((address_space(1))) void*)(g), \
    (__attribute__((address_space(3))) void*)(l), 16, 0, 0)

static __device__ __forceinline__ unsigned short f2bf(float x){
  unsigned int u = __float_as_uint(x);
  u += 0x7fffu + ((u >> 16) & 1u);
  return (unsigned short)(u >> 16);
}
static __device__ __forceinline__ float bf2f(unsigned short h){
  return __uint_as_float(((unsigned int)h) << 16);
}
static __device__ __forceinline__ f32x4 mfma16(bf8_t a, bf8_t b, f32x4 c){
  return __builtin_amdgcn_mfma_f32_16x16x32_bf16(a, b, c, 0, 0, 0);
}

// ---------- conversion / repack kernels ----------
__global__ __launch_bounds__(256) void k_cvt(const float* __restrict__ src,
    unsigned short* __restrict__ dst, int n8){
  for (int i = blockIdx.x*256 + threadIdx.x; i < n8; i += gridDim.x*256){
    float4 v0 = ((const float4*)src)[i*2];
    float4 v1 = ((const float4*)src)[i*2+1];
    u16x8 o;
    o[0]=f2bf(v0.x); o[1]=f2bf(v0.y); o[2]=f2bf(v0.z); o[3]=f2bf(v0.w);
    o[4]=f2bf(v1.x); o[5]=f2bf(v1.y); o[6]=f2bf(v1.z); o[7]=f2bf(v1.w);
    ((u16x8*)dst)[i] = o;
  }
}

// dst[kg][c][i] = bf16(src[(8kg+i)*N + c]);  batched over blockIdx.y
__global__ __launch_bounds__(256) void k_pack8(const float* __restrict__ src,
    unsigned short* __restrict__ dst, int K, int N){
  const size_t base = (size_t)blockIdx.y * K * N;
  int idx = blockIdx.x*256 + threadIdx.x;     // idx = kg*N + c
  int kg = idx / N, c = idx % N;
  const float* s = src + base + (size_t)(kg*8)*N + c;
  u16x8 o;
  #pragma unroll
  for (int i=0;i<8;i++) o[i] = f2bf(s[(size_t)i*N]);
  ((u16x8*)(dst + base))[idx] = o;
}

// ---------- shared rf-features + LayerNorm epilogue ----------
// acc[rt][ct][j] = z for row (n0 + row0 + rt*16 + 4*(l>>4)+j), col (colhalf*256 + ct*16 + (l&15))
// sum(f^2) over 1024 features = 1 exactly (cos^2+sin^2), so var = 1/1024 - mu^2.
template<int RT>
static __device__ __forceinline__ void rf_ln_store(f32x4 (&acc)[RT][16],
    unsigned short* __restrict__ phiM, float* rowp, int row0,
    int n0, int colhalf, int l){
  const float scale = 0.044194173824159216f;  // 1/sqrt(512)
  const int g = l >> 4, li = l & 15;
  float part[RT][4];
  #pragma unroll
  for (int rt=0; rt<RT; rt++){
    #pragma unroll
    for (int j=0;j<4;j++){
      float s = 0.f;
      #pragma unroll
      for (int ct=0; ct<16; ct++){
        float sn, cs; __sincosf(acc[rt][ct][j], &sn, &cs);
        s += sn + cs;
      }
      #pragma unroll
      for (int off=1; off<16; off<<=1) s += __shfl_xor(s, off);
      part[rt][j] = s;
    }
  }
  if (li == 0){
    #pragma unroll
    for (int rt=0; rt<RT; rt++)
      #pragma unroll
      for (int j=0;j<4;j++)
        rowp[(row0 + rt*16 + 4*g + j)*2 + colhalf] = part[rt][j];
  }
  __syncthreads();
  #pragma unroll
  for (int rt=0; rt<RT; rt++){
    #pragma unroll
    for (int j=0;j<4;j++){
      int rb = row0 + rt*16 + 4*g + j;
      float tot = rowp[rb*2+0] + rowp[rb*2+1];
      float mu = tot * (scale / 1024.0f);
      float rs = 1.0f / sqrtf((1.0f/1024.0f) - mu*mu + 1e-5f);
      size_t base = (size_t)(n0 + rb) * 1024;
      #pragma unroll
      for (int ct=0; ct<16; ct++){
        int c = colhalf*256 + ct*16 + li;
        float sn, cs; __sincosf(acc[rt][ct][j], &sn, &cs);
        phiM[base + c]       = f2bf((cs*scale - mu)*rs);
        phiM[base + 512 + c] = f2bf((sn*scale - mu)*rs);
      }
    }
  }
}

// ---------- K1: z1 = Xb @ Om1f[m] -> rf/LN -> phi ----------
// block: 64 rows x 512 cols; wave w: rows (w>>1)*32..+31, cols (w&1)*256..+255
// 2-phase double-buffered B staging.
__global__ __launch_bounds__(256) void k_phi1(const unsigned short* __restrict__ Xb,
    const unsigned short* __restrict__ Om1f, unsigned short* __restrict__ phi){
  const int m = blockIdx.y, n0 = blockIdx.x*64;
  const int t = threadIdx.x, w = t>>6, l = t&63;
  const int g = l>>4, li = l&15;
  const int wrow = (w>>1)*32, ch = w&1;
  const int wvb = (t & ~63);
  __shared__ unsigned short Bs[2][16384];   // 2 x 32KB
  __shared__ float rowp[128];
  f32x4 acc[2][16];
  const f32x4 z4 = {0.f,0.f,0.f,0.f};
  #pragma unroll
  for (int rt=0;rt<2;rt++)
    #pragma unroll
    for (int ct=0;ct<16;ct++) acc[rt][ct] = z4;
  const unsigned short* bsrc = Om1f + (size_t)m*524288;
  const unsigned short* ar0 = Xb + (size_t)(n0 + wrow + li)*1024 + g*8;
  const unsigned short* ar1 = ar0 + 16*1024;
  int cur = 0;
  #pragma unroll
  for (int it=0; it<8; it++)
    GLD16(bsrc + it*2048 + t*8, &Bs[0][0] + it*2048 + wvb*8);
  bf8_t a0c = *(const bf8_t*)(ar0);
  bf8_t a1c = *(const bf8_t*)(ar1);
  __syncthreads();
  for (int ks=0; ks<32; ks++){
    int ksn = (ks+1 < 32) ? ks+1 : ks;
    #pragma unroll
    for (int it=0; it<8; it++)
      GLD16(bsrc + (size_t)ksn*16384 + it*2048 + t*8, &Bs[cur^1][0] + it*2048 + wvb*8);
    bf8_t a0n = *(const bf8_t*)(ar0 + ksn*32);
    bf8_t a1n = *(const bf8_t*)(ar1 + ksn*32);
    #pragma unroll
    for (int ct=0; ct<16; ct++){
      bf8_t b = *(const bf8_t*)(&Bs[cur][0] + g*4096 + (ch*256 + ct*16 + li)*8);
      acc[0][ct] = mfma16(a0c, b, acc[0][ct]);
      acc[1][ct] = mfma16(a1c, b, acc[1][ct]);
    }
    __syncthreads();
    a0c = a0n; a1c = a1n; cur ^= 1;
  }
  rf_ln_store<2>(acc, phi + (size_t)m*NTOT*1024, rowp, wrow, n0, ch, l);
}

// ---------- K2: fused h=phi1@W1+b1 (LDS) ; z2=h@Om2 -> rf/LN -> phi in place ----------
// 512 threads, 64-row block; wave w: rows (w>>1)*16..+15, cols (w&1)*256..+255
__global__ __launch_bounds__(512) void k_phi2(unsigned short* __restrict__ phi,
    const unsigned short* __restrict__ W1f, const float* __restrict__ b1,
    const unsigned short* __restrict__ Om2f){
  const int m = blockIdx.y, n0 = blockIdx.x*64;
  const int t = threadIdx.x, w = t>>6, l = t&63;
  const int g = l>>4, li = l&15;
  const int wrow = (w>>1)*16, ch = w&1;
  const int wvb = (t & ~63);
  __shared__ unsigned short Bs[2][16384];   // 64KB
  __shared__ unsigned short hs[64*520];     // 66.5KB, padded row stride
  __shared__ float rowp[128];
  f32x4 acc[1][16];
  const f32x4 z4 = {0.f,0.f,0.f,0.f};
  #pragma unroll
  for (int ct=0;ct<16;ct++) acc[0][ct] = z4;
  const unsigned short* arow = phi + ((size_t)m*NTOT + n0 + wrow + li)*1024 + g*8;
  int cur = 0;
  // ---- stage 1: K=1024, B=W1f ----
  #pragma unroll
  for (int it=0; it<4; it++)
    GLD16(W1f + it*4096 + t*8, &Bs[0][0] + it*4096 + wvb*8);
  bf8_t ac = *(const bf8_t*)(arow);
  __syncthreads();
  for (int ks=0; ks<32; ks++){
    int ksn = (ks+1 < 32) ? ks+1 : ks;
    #pragma unroll
    for (int it=0; it<4; it++)
      GLD16(W1f + (size_t)ksn*16384 + it*4096 + t*8, &Bs[cur^1][0] + it*4096 + wvb*8);
    bf8_t an = *(const bf8_t*)(arow + ksn*32);
    #pragma unroll
    for (int ct=0; ct<16; ct++){
      bf8_t b = *(const bf8_t*)(&Bs[cur][0] + g*4096 + (ch*256 + ct*16 + li)*8);
      acc[0][ct] = mfma16(ac, b, acc[0][ct]);
    }
    __syncthreads();
    ac = an; cur ^= 1;
  }
  // h -> LDS (bf16, +b1), and prologue-stage Om2f tile 0 into the free buffer
  #pragma unroll
  for (int ct=0; ct<16; ct++){
    int c = ch*256 + ct*16 + li;
    float bv = b1[c];
    #pragma unroll
    for (int j=0;j<4;j++){
      int row = wrow + 4*g + j;
      hs[row*520 + c] = f2bf(acc[0][ct][j] + bv);
    }
  }
  const unsigned short* b2src = Om2f + (size_t)m*262144;
  #pragma unroll
  for (int it=0; it<4; it++)
    GLD16(b2src + it*4096 + t*8, &Bs[cur^1][0] + it*4096 + wvb*8);
  __syncthreads();
  cur ^= 1;
  // ---- stage 2: K=512, A=hs, B=Om2f ----
  #pragma unroll
  for (int ct=0;ct<16;ct++) acc[0][ct] = z4;
  for (int ks=0; ks<16; ks++){
    int ksn = (ks+1 < 16) ? ks+1 : ks;
    #pragma unroll
    for (int it=0; it<4; it++)
      GLD16(b2src + (size_t)ksn*16384 + it*4096 + t*8, &Bs[cur^1][0] + it*4096 + wvb*8);
    bf8_t a = *(const bf8_t*)(&hs[(wrow + li)*520 + ks*32 + g*8]);
    #pragma unroll
    for (int ct=0; ct<16; ct++){
      bf8_t b = *(const bf8_t*)(&Bs[cur][0] + g*4096 + (ch*256 + ct*16 + li)*8);
      acc[0][ct] = mfma16(a, b, acc[0][ct]);
    }
    __syncthreads();
    cur ^= 1;
  }
  rf_ln_store<1>(acc, phi + (size_t)m*NTOT*1024, rowp, wrow, n0, ch, l);
}

// ---------- K3: emb = phi2 @ W2f + b2 -> bf16 ----------
// block: 64 rows x 256 cols; wave w: rows w*16, all 256 cols; dbuf staging
__global__ __launch_bounds__(256) void k_emb(const unsigned short* __restrict__ phi,
    const unsigned short* __restrict__ W2f, const float* __restrict__ b2,
    unsigned short* __restrict__ emb){
  const int m = blockIdx.y, n0 = blockIdx.x*64;
  const int t = threadIdx.x, w = t>>6, l = t&63;
  const int g = l>>4, li = l&15;
  const int wvb = (t & ~63);
  __shared__ unsigned short Bs[2][8192];    // 2 x 16KB
  f32x4 acc[16];
  const f32x4 z4 = {0.f,0.f,0.f,0.f};
  #pragma unroll
  for (int ct=0;ct<16;ct++) acc[ct] = z4;
  const unsigned short* arow = phi + ((size_t)m*NTOT + n0 + w*16 + li)*1024 + g*8;
  int cur = 0;
  #pragma unroll
  for (int it=0; it<4; it++)
    GLD16(W2f + it*2048 + t*8, &Bs[0][0] + it*2048 + wvb*8);
  bf8_t ac = *(const bf8_t*)(arow);
  __syncthreads();
  for (int ks=0; ks<32; ks++){
    int ksn = (ks+1 < 32) ? ks+1 : ks;
    #pragma unroll
    for (int it=0; it<4; it++)
      GLD16(W2f + (size_t)ksn*8192 + it*2048 + t*8, &Bs[cur^1][0] + it*2048 + wvb*8);
    bf8_t an = *(const bf8_t*)(arow + ksn*32);
    #pragma unroll
    for (int ct=0; ct<16; ct++){
      bf8_t b = *(const bf8_t*)(&Bs[cur][0] + g*2048 + (ct*16 + li)*8);
      acc[ct] = mfma16(ac, b, acc[ct]);
    }
    __syncthreads();
    ac = an; cur ^= 1;
  }
  #pragma unroll
  for (int ct=0; ct<16; ct++){
    int c = ct*16 + li;
    float bv = b2[c];
    #pragma unroll
    for (int j=0;j<4;j++)
      emb[((size_t)m*NTOT + n0 + w*16 + 4*g + j)*256 + c] = f2bf(acc[ct][j] + bv);
  }
}

// ---------- K4: scores -> p = exp((emb.Ws + bs)/16) ----------
__global__ __launch_bounds__(256) void k_scores(const unsigned short* __restrict__ emb,
    const float* __restrict__ Wsm, const float* __restrict__ bsv, float* __restrict__ p){
  const int m = blockIdx.y;
  const int n = blockIdx.x*256 + threadIdx.x;
  __shared__ float Wss[1024];
  ((float4*)Wss)[threadIdx.x] = ((const float4*)Wsm)[threadIdx.x];
  __syncthreads();
  const u16x8* er = (const u16x8*)(emb + ((size_t)m*NTOT + n)*256);
  float a0=0.f,a1=0.f,a2=0.f,a3=0.f;
  for (int d8=0; d8<32; d8++){
    u16x8 e = er[d8];
    #pragma unroll
    for (int i=0;i<8;i++){
      float ev = bf2f(e[i]);
      const float* wv = &Wss[(d8*8+i)*4];
      a0 += ev*wv[0]; a1 += ev*wv[1]; a2 += ev*wv[2]; a3 += ev*wv[3];
    }
  }
  float4 o;
  o.x = expf((a0 + bsv[0]) * 0.0625f);
  o.y = expf((a1 + bsv[1]) * 0.0625f);
  o.z = expf((a2 + bsv[2]) * 0.0625f);
  o.w = expf((a3 + bsv[3]) * 0.0625f);
  ((float4*)p)[(size_t)m*NTOT + n] = o;
}

// ---------- K5: bag start offsets ----------
__global__ void k_starts(const int* __restrict__ idx, int* __restrict__ starts){
  int t = threadIdx.x;
  if (t <= NBAG){
    int lo = 0, hi = NTOT;
    while (lo < hi){ int mid = (lo + hi) >> 1; if (idx[mid] < t) lo = mid + 1; else hi = mid; }
    starts[t] = lo;
  }
}

// ---------- K6: en = relu(emb @ Wmf + bm) -> bf16 ----------
__global__ __launch_bounds__(256) void k_embnew(const unsigned short* __restrict__ emb,
    const unsigned short* __restrict__ Wmf, const float* __restrict__ bm,
    unsigned short* __restrict__ en){
  const int m = blockIdx.y, n0 = blockIdx.x*64;
  const int t = threadIdx.x, w = t>>6, l = t&63;
  const int g = l>>4, li = l&15;
  const int wvb = (t & ~63);
  __shared__ unsigned short Bs[32768];   // full Wmf [32][128][8] = 64KB
  #pragma unroll
  for (int it=0; it<16; it++)
    GLD16(Wmf + it*2048 + t*8, Bs + it*2048 + wvb*8);
  asm volatile("s_waitcnt vmcnt(0)" ::: "memory");
  __syncthreads();
  f32x4 acc[8];
  const f32x4 z4 = {0.f,0.f,0.f,0.f};
  #pragma unroll
  for (int ct=0;ct<8;ct++) acc[ct] = z4;
  const unsigned short* arow = emb + ((size_t)m*NTOT + n0 + w*16 + li)*256 + g*8;
  #pragma unroll
  for (int ks=0; ks<8; ks++){
    bf8_t a = *(const bf8_t*)(arow + ks*32);
    #pragma unroll
    for (int ct=0; ct<8; ct++){
      bf8_t b = *(const bf8_t*)(Bs + (ks*4+g)*1024 + (ct*16 + li)*8);
      acc[ct] = mfma16(a, b, acc[ct]);
    }
  }
  #pragma unroll
  for (int ct=0; ct<8; ct++){
    int c = ct*16 + li;
    float bv = bm[c];
    #pragma unroll
    for (int j=0;j<4;j++)
      en[((size_t)m*NTOT + n0 + w*16 + 4*g + j)*128 + c] = f2bf(fmaxf(acc[ct][j] + bv, 0.f));
  }
}

// ---------- K7: per (bag,m): seg = sum p; out[e] = sum_n en * p[k]/seg[k] ----------
__global__ __launch_bounds__(256) void k_pool(const unsigned short* __restrict__ en,
    const float* __restrict__ p, const int* __restrict__ starts, float* __restrict__ out){
  const int b = blockIdx.x, m = blockIdx.y;
  const int t = threadIdx.x;
  const int s0 = starts[b], s1 = starts[b+1];
  float sp0=0.f,sp1=0.f,sp2=0.f,sp3=0.f;
  for (int n = s0 + t; n < s1; n += 256){
    float4 pv = ((const float4*)p)[(size_t)m*NTOT + n];
    sp0 += pv.x; sp1 += pv.y; sp2 += pv.z; sp3 += pv.w;
  }
  #pragma unroll
  for (int off=1; off<64; off<<=1){
    sp0 += __shfl_xor(sp0, off); sp1 += __shfl_xor(sp1, off);
    sp2 += __shfl_xor(sp2, off); sp3 += __shfl_xor(sp3, off);
  }
  __shared__ float wred[4][4];
  __shared__ float winv[4];
  if ((t & 63) == 0){ wred[t>>6][0]=sp0; wred[t>>6][1]=sp1; wred[t>>6][2]=sp2; wred[t>>6][3]=sp3; }
  __syncthreads();
  if (t < 4){
    float s = wred[0][t] + wred[1][t] + wred[2][t] + wred[3][t];
    winv[t] = (s > 0.f) ? 1.0f / s : 0.f;
  }
  __syncthreads();
  const int e = t & 127, half = t >> 7;
  const int k = e >> 5;
  float accv = 0.f;
  for (int n = s0 + half; n < s1; n += 2){
    float wq = p[((size_t)m*NTOT + n)*4 + k];
    float v = bf2f(en[((size_t)m*NTOT + n)*128 + e]);
    accv = fmaf(v, wq, accv);
  }
  accv *= winv[k];
  __shared__ float ac2[2][128];
  ac2[half][e] = accv;
  __syncthreads();
  if (t < 128) out[((size_t)b*NMC + m)*128 + t] = ac2[0][t] + ac2[1][t];
}

extern "C" void kernel_launch(void* const* d_in, const int* in_sizes, int n_in,
                              void* d_out, int out_size, void* d_ws, size_t ws_size,
                              hipStream_t stream) {
  const float* X    = (const float*)d_in[0];
  const int*   Xidx = (const int*)  d_in[1];
  const float* Om1  = (const float*)d_in[2];
  const float* Om2  = (const float*)d_in[3];
  const float* W1   = (const float*)d_in[4];
  const float* b1   = (const float*)d_in[5];
  const float* W2   = (const float*)d_in[6];
  const float* b2   = (const float*)d_in[7];
  const float* Wsm  = (const float*)d_in[8];
  const float* bsv  = (const float*)d_in[9];
  const float* Wm   = (const float*)d_in[10];
  const float* bm   = (const float*)d_in[11];
  float* out = (float*)d_out;

  char* ws = (char*)d_ws;
  unsigned short* phi  = (unsigned short*)(ws);                    // 128MB [m][n][1024]
  unsigned short* Xb   = (unsigned short*)(ws + 134217728ull);     // 32MB (dead after k_phi1)
  unsigned short* emb  = (unsigned short*)(ws + 134217728ull);     // 32MB (aliases Xb)
  unsigned short* en   = (unsigned short*)(ws + 167772160ull);     // 16MB
  float* p             = (float*)(ws + 184549376ull);              // 1MB
  int* starts          = (int*)(ws + 185597952ull);                // 1KB
  unsigned short* Om1f = (unsigned short*)(ws + 185598976ull);     // 4MB
  unsigned short* W1f  = (unsigned short*)(ws + 189793280ull);     // 1MB
  unsigned short* Om2f = (unsigned short*)(ws + 190841856ull);     // 2MB
  unsigned short* W2f  = (unsigned short*)(ws + 192939008ull);     // 0.5MB
  unsigned short* Wmf  = (unsigned short*)(ws + 193463296ull);     // 64KB

  k_cvt   <<<2048, 256, 0, stream>>>(X, Xb, NTOT*1024/8);
  k_pack8 <<<dim3(256,4), 256, 0, stream>>>(Om1, Om1f, 1024, 512);
  k_pack8 <<<dim3(256,1), 256, 0, stream>>>(W1,  W1f,  1024, 512);
  k_pack8 <<<dim3(128,4), 256, 0, stream>>>(Om2, Om2f, 512,  512);
  k_pack8 <<<dim3(128,1), 256, 0, stream>>>(W2,  W2f,  1024, 256);
  k_pack8 <<<dim3(16,1),  256, 0, stream>>>(Wm,  Wmf,  256,  128);
  k_phi1  <<<dim3(256,4), 256, 0, stream>>>(Xb, Om1f, phi);
  k_phi2  <<<dim3(256,4), 512, 0, stream>>>(phi, W1f, b1, Om2f);
  k_emb   <<<dim3(256,4), 256, 0, stream>>>(phi, W2f, b2, emb);
  k_scores<<<dim3(64,4),  256, 0, stream>>>(emb, Wsm, bsv, p);
  k_embnew<<<dim3(256,4), 256, 0, stream>>>(emb, Wmf, bm, en);
  k_starts<<<1, 128, 0, stream>>>(Xidx, starts);
  k_pool  <<<dim3(64,4),  256, 0, stream>>>(en, p, starts, out);
}

// Round 5
// 530.510 us; speedup vs baseline: 5.4123x; 1.2466x over previous
//
#include <hip/hip_runtime.h>

#define NTOT 16384
#define NBAG 64
#define NMC  4

typedef __attribute__((ext_vector_type(8))) short bf8_t;       // 8 x bf16 payload
typedef __attribute__((ext_vector_type(4))) float f32x4;
typedef __attribute__((ext_vector_type(8))) unsigned short u16x8;

#define GLD16(g, l) __builtin_amdgcn_global_load_lds( \
    (const __attribute__((address_space(1))) void*)(g), \
    (__attribute__((address_space(3))) void*)(l), 16, 0, 0)

static __device__ __forceinline__ unsigned short f2bf(float x){
  unsigned int u = __float_as_uint(x);
  u += 0x7fffu + ((u >> 16) & 1u);
  return (unsigned short)(u >> 16);
}
static __device__ __forceinline__ float bf2f(unsigned short h){
  return __uint_as_float(((unsigned int)h) << 16);
}
static __device__ __forceinline__ f32x4 mfma16(bf8_t a, bf8_t b, f32x4 c){
  return __builtin_amdgcn_mfma_f32_16x16x32_bf16(a, b, c, 0, 0, 0);
}

// ---------- conversion / repack kernels ----------
__global__ __launch_bounds__(256) void k_cvt(const float* __restrict__ src,
    unsigned short* __restrict__ dst, int n8){
  for (int i = blockIdx.x*256 + threadIdx.x; i < n8; i += gridDim.x*256){
    float4 v0 = ((const float4*)src)[i*2];
    float4 v1 = ((const float4*)src)[i*2+1];
    u16x8 o;
    o[0]=f2bf(v0.x); o[1]=f2bf(v0.y); o[2]=f2bf(v0.z); o[3]=f2bf(v0.w);
    o[4]=f2bf(v1.x); o[5]=f2bf(v1.y); o[6]=f2bf(v1.z); o[7]=f2bf(v1.w);
    ((u16x8*)dst)[i] = o;
  }
}

// dst[kg][c][i] = bf16(src[(8kg+i)*N + c]);  batched over blockIdx.y
__global__ __launch_bounds__(256) void k_pack8(const float* __restrict__ src,
    unsigned short* __restrict__ dst, int K, int N){
  const size_t base = (size_t)blockIdx.y * K * N;
  int idx = blockIdx.x*256 + threadIdx.x;     // idx = kg*N + c
  int kg = idx / N, c = idx % N;
  const float* s = src + base + (size_t)(kg*8)*N + c;
  u16x8 o;
  #pragma unroll
  for (int i=0;i<8;i++) o[i] = f2bf(s[(size_t)i*N]);
  ((u16x8*)(dst + base))[idx] = o;
}

// ---------- shared rf-features + LayerNorm epilogue ----------
// acc[rt][ct][j] = z for row (n0 + row0 + rt*16 + 4*(l>>4)+j), col (ch*256 + ct*16 + (l&15))
// sum(f^2) over 1024 features = 1 exactly (cos^2+sin^2), so var = 1/1024 - mu^2.
template<int RT>
static __device__ __forceinline__ void rf_ln_store(f32x4 (&acc)[RT][16],
    unsigned short* __restrict__ phiM, float* rowp, int row0,
    int n0, int ch, int l){
  const float scale = 0.044194173824159216f;  // 1/sqrt(512)
  const int g = l >> 4, li = l & 15;
  float part[RT][4];
  #pragma unroll
  for (int rt=0; rt<RT; rt++){
    #pragma unroll
    for (int j=0;j<4;j++){
      float s = 0.f;
      #pragma unroll
      for (int ct=0; ct<16; ct++){
        float sn, cs; __sincosf(acc[rt][ct][j], &sn, &cs);
        s += sn + cs;
      }
      #pragma unroll
      for (int off=1; off<16; off<<=1) s += __shfl_xor(s, off);
      part[rt][j] = s;
    }
  }
  __syncthreads();   // all MFMA phases done; rowp safe to write
  if (li == 0){
    #pragma unroll
    for (int rt=0; rt<RT; rt++)
      #pragma unroll
      for (int j=0;j<4;j++)
        rowp[(row0 + rt*16 + 4*g + j)*2 + ch] = part[rt][j];
  }
  __syncthreads();
  #pragma unroll
  for (int rt=0; rt<RT; rt++){
    #pragma unroll
    for (int j=0;j<4;j++){
      int rb = row0 + rt*16 + 4*g + j;
      float tot = rowp[rb*2+0] + rowp[rb*2+1];
      float mu = tot * (scale / 1024.0f);
      float rs = 1.0f / sqrtf((1.0f/1024.0f) - mu*mu + 1e-5f);
      size_t base = (size_t)(n0 + rb) * 1024;
      #pragma unroll
      for (int ct=0; ct<16; ct++){
        int c = ch*256 + ct*16 + li;
        float sn, cs; __sincosf(acc[rt][ct][j], &sn, &cs);
        phiM[base + c]       = f2bf((cs*scale - mu)*rs);
        phiM[base + 512 + c] = f2bf((sn*scale - mu)*rs);
      }
    }
  }
}

// ================= depth-2 pipelined GEMM kernels =================
// Common: 512 thr (8 waves), 128-row x 512-col tile (RT=2), 4-buffer ring,
// counted vmcnt(12) = iters {t, t-1} in flight (6 vmem ops/iter), 1 barrier/iter.

// ---------- K1: z1 = Xb @ Om1f[m] -> rf/LN -> phi ----------
__global__ __launch_bounds__(512,2) void k_phi1(const unsigned short* __restrict__ Xb,
    const unsigned short* __restrict__ Om1f, unsigned short* __restrict__ phi){
  const int m = blockIdx.y, n0 = blockIdx.x*128;
  const int t = threadIdx.x, w = t>>6, l = t&63;
  const int g = l>>4, li = l&15;
  const int wrg = w>>1, ch = w&1;
  const int wvb = (t & ~63);
  __shared__ unsigned short Bs[4][16384];   // 4 x 32KB ring
  __shared__ float rowp[256];
  f32x4 acc[2][16];
  const f32x4 z4 = {0.f,0.f,0.f,0.f};
  #pragma unroll
  for (int rt=0;rt<2;rt++)
    #pragma unroll
    for (int ct=0;ct<16;ct++) acc[rt][ct] = z4;
  const unsigned short* bsrc = Om1f + (size_t)m*524288;
  const unsigned short* ar0 = Xb + (size_t)(n0 + wrg*32 + li)*1024 + g*8;
  const unsigned short* ar1 = ar0 + 16*1024;
  #pragma unroll
  for (int it=0; it<4; it++) GLD16(bsrc + it*4096 + t*8, &Bs[0][0] + it*4096 + wvb*8);
  #pragma unroll
  for (int it=0; it<4; it++) GLD16(bsrc + 16384 + it*4096 + t*8, &Bs[1][0] + it*4096 + wvb*8);
  bf8_t a0c = *(const bf8_t*)(ar0);       bf8_t a1c = *(const bf8_t*)(ar1);
  bf8_t a0n = *(const bf8_t*)(ar0 + 32);  bf8_t a1n = *(const bf8_t*)(ar1 + 32);
  for (int ks=0; ks<32; ks++){
    int ksn = ks+2 < 32 ? ks+2 : 31;
    const unsigned short* sb = bsrc + (size_t)ksn*16384;
    unsigned short* db = &Bs[(ks+2)&3][0];
    #pragma unroll
    for (int it=0; it<4; it++) GLD16(sb + it*4096 + t*8, db + it*4096 + wvb*8);
    bf8_t a0nn = *(const bf8_t*)(ar0 + ksn*32);
    bf8_t a1nn = *(const bf8_t*)(ar1 + ksn*32);
    asm volatile("s_waitcnt vmcnt(12)" ::: "memory");
    __builtin_amdgcn_sched_barrier(0);
    __builtin_amdgcn_s_barrier();
    __builtin_amdgcn_sched_barrier(0);
    const unsigned short* bb = &Bs[ks&3][0] + g*4096 + (ch*256)*8;
    __builtin_amdgcn_s_setprio(1);
    #pragma unroll
    for (int ct=0; ct<16; ct++){
      bf8_t b = *(const bf8_t*)(bb + (ct*16 + li)*8);
      acc[0][ct] = mfma16(a0c, b, acc[0][ct]);
      acc[1][ct] = mfma16(a1c, b, acc[1][ct]);
    }
    __builtin_amdgcn_s_setprio(0);
    a0c=a0n; a1c=a1n; a0n=a0nn; a1n=a1nn;
  }
  rf_ln_store<2>(acc, phi + (size_t)m*NTOT*1024, rowp, wrg*32, n0, ch, l);
}

// ---------- K2a: h = phi @ W1f + b1 -> bf16 ----------
__global__ __launch_bounds__(512,2) void k_phi2a(const unsigned short* __restrict__ phi,
    const unsigned short* __restrict__ W1f, const float* __restrict__ b1,
    unsigned short* __restrict__ h){
  const int m = blockIdx.y, n0 = blockIdx.x*128;
  const int t = threadIdx.x, w = t>>6, l = t&63;
  const int g = l>>4, li = l&15;
  const int wrg = w>>1, ch = w&1;
  const int wvb = (t & ~63);
  __shared__ unsigned short Bs[4][16384];
  f32x4 acc[2][16];
  const f32x4 z4 = {0.f,0.f,0.f,0.f};
  #pragma unroll
  for (int rt=0;rt<2;rt++)
    #pragma unroll
    for (int ct=0;ct<16;ct++) acc[rt][ct] = z4;
  const unsigned short* ar0 = phi + ((size_t)m*NTOT + n0 + wrg*32 + li)*1024 + g*8;
  const unsigned short* ar1 = ar0 + 16*1024;
  #pragma unroll
  for (int it=0; it<4; it++) GLD16(W1f + it*4096 + t*8, &Bs[0][0] + it*4096 + wvb*8);
  #pragma unroll
  for (int it=0; it<4; it++) GLD16(W1f + 16384 + it*4096 + t*8, &Bs[1][0] + it*4096 + wvb*8);
  bf8_t a0c = *(const bf8_t*)(ar0);       bf8_t a1c = *(const bf8_t*)(ar1);
  bf8_t a0n = *(const bf8_t*)(ar0 + 32);  bf8_t a1n = *(const bf8_t*)(ar1 + 32);
  for (int ks=0; ks<32; ks++){
    int ksn = ks+2 < 32 ? ks+2 : 31;
    const unsigned short* sb = W1f + (size_t)ksn*16384;
    unsigned short* db = &Bs[(ks+2)&3][0];
    #pragma unroll
    for (int it=0; it<4; it++) GLD16(sb + it*4096 + t*8, db + it*4096 + wvb*8);
    bf8_t a0nn = *(const bf8_t*)(ar0 + ksn*32);
    bf8_t a1nn = *(const bf8_t*)(ar1 + ksn*32);
    asm volatile("s_waitcnt vmcnt(12)" ::: "memory");
    __builtin_amdgcn_sched_barrier(0);
    __builtin_amdgcn_s_barrier();
    __builtin_amdgcn_sched_barrier(0);
    const unsigned short* bb = &Bs[ks&3][0] + g*4096 + (ch*256)*8;
    __builtin_amdgcn_s_setprio(1);
    #pragma unroll
    for (int ct=0; ct<16; ct++){
      bf8_t b = *(const bf8_t*)(bb + (ct*16 + li)*8);
      acc[0][ct] = mfma16(a0c, b, acc[0][ct]);
      acc[1][ct] = mfma16(a1c, b, acc[1][ct]);
    }
    __builtin_amdgcn_s_setprio(0);
    a0c=a0n; a1c=a1n; a0n=a0nn; a1n=a1nn;
  }
  #pragma unroll
  for (int rt=0; rt<2; rt++){
    #pragma unroll
    for (int ct=0; ct<16; ct++){
      int c = ch*256 + ct*16 + li;
      float bv = b1[c];
      #pragma unroll
      for (int j=0;j<4;j++)
        h[((size_t)m*NTOT + n0 + wrg*32 + rt*16 + 4*g + j)*512 + c] = f2bf(acc[rt][ct][j] + bv);
    }
  }
}

// ---------- K2b: z2 = h @ Om2f[m] -> rf/LN -> phi (in place) ----------
__global__ __launch_bounds__(512,2) void k_phi2b(const unsigned short* __restrict__ h,
    const unsigned short* __restrict__ Om2f, unsigned short* __restrict__ phi){
  const int m = blockIdx.y, n0 = blockIdx.x*128;
  const int t = threadIdx.x, w = t>>6, l = t&63;
  const int g = l>>4, li = l&15;
  const int wrg = w>>1, ch = w&1;
  const int wvb = (t & ~63);
  __shared__ unsigned short Bs[4][16384];
  __shared__ float rowp[256];
  f32x4 acc[2][16];
  const f32x4 z4 = {0.f,0.f,0.f,0.f};
  #pragma unroll
  for (int rt=0;rt<2;rt++)
    #pragma unroll
    for (int ct=0;ct<16;ct++) acc[rt][ct] = z4;
  const unsigned short* bsrc = Om2f + (size_t)m*262144;
  const unsigned short* ar0 = h + ((size_t)m*NTOT + n0 + wrg*32 + li)*512 + g*8;
  const unsigned short* ar1 = ar0 + 16*512;
  #pragma unroll
  for (int it=0; it<4; it++) GLD16(bsrc + it*4096 + t*8, &Bs[0][0] + it*4096 + wvb*8);
  #pragma unroll
  for (int it=0; it<4; it++) GLD16(bsrc + 16384 + it*4096 + t*8, &Bs[1][0] + it*4096 + wvb*8);
  bf8_t a0c = *(const bf8_t*)(ar0);       bf8_t a1c = *(const bf8_t*)(ar1);
  bf8_t a0n = *(const bf8_t*)(ar0 + 32);  bf8_t a1n = *(const bf8_t*)(ar1 + 32);
  for (int ks=0; ks<16; ks++){
    int ksn = ks+2 < 16 ? ks+2 : 15;
    const unsigned short* sb = bsrc + (size_t)ksn*16384;
    unsigned short* db = &Bs[(ks+2)&3][0];
    #pragma unroll
    for (int it=0; it<4; it++) GLD16(sb + it*4096 + t*8, db + it*4096 + wvb*8);
    bf8_t a0nn = *(const bf8_t*)(ar0 + ksn*32);
    bf8_t a1nn = *(const bf8_t*)(ar1 + ksn*32);
    asm volatile("s_waitcnt vmcnt(12)" ::: "memory");
    __builtin_amdgcn_sched_barrier(0);
    __builtin_amdgcn_s_barrier();
    __builtin_amdgcn_sched_barrier(0);
    const unsigned short* bb = &Bs[ks&3][0] + g*4096 + (ch*256)*8;
    __builtin_amdgcn_s_setprio(1);
    #pragma unroll
    for (int ct=0; ct<16; ct++){
      bf8_t b = *(const bf8_t*)(bb + (ct*16 + li)*8);
      acc[0][ct] = mfma16(a0c, b, acc[0][ct]);
      acc[1][ct] = mfma16(a1c, b, acc[1][ct]);
    }
    __builtin_amdgcn_s_setprio(0);
    a0c=a0n; a1c=a1n; a0n=a0nn; a1n=a1nn;
  }
  rf_ln_store<2>(acc, phi + (size_t)m*NTOT*1024, rowp, wrg*32, n0, ch, l);
}

// ---------- K3: emb = phi2 @ W2f + b2 -> bf16 ----------
// 512 thr, 128 rows x 256 cols; wave w: rows w*16, all 256 cols
__global__ __launch_bounds__(512,4) void k_emb(const unsigned short* __restrict__ phi,
    const unsigned short* __restrict__ W2f, const float* __restrict__ b2,
    unsigned short* __restrict__ emb){
  const int m = blockIdx.y, n0 = blockIdx.x*128;
  const int t = threadIdx.x, w = t>>6, l = t&63;
  const int g = l>>4, li = l&15;
  const int wvb = (t & ~63);
  __shared__ unsigned short Bs[4][8192];   // 4 x 16KB ring
  f32x4 acc[16];
  const f32x4 z4 = {0.f,0.f,0.f,0.f};
  #pragma unroll
  for (int ct=0;ct<16;ct++) acc[ct] = z4;
  const unsigned short* arow = phi + ((size_t)m*NTOT + n0 + w*16 + li)*1024 + g*8;
  #pragma unroll
  for (int it=0; it<2; it++) GLD16(W2f + it*4096 + t*8, &Bs[0][0] + it*4096 + wvb*8);
  #pragma unroll
  for (int it=0; it<2; it++) GLD16(W2f + 8192 + it*4096 + t*8, &Bs[1][0] + it*4096 + wvb*8);
  bf8_t ac = *(const bf8_t*)(arow);
  bf8_t an = *(const bf8_t*)(arow + 32);
  for (int ks=0; ks<32; ks++){
    int ksn = ks+2 < 32 ? ks+2 : 31;
    const unsigned short* sb = W2f + (size_t)ksn*8192;
    unsigned short* db = &Bs[(ks+2)&3][0];
    #pragma unroll
    for (int it=0; it<2; it++) GLD16(sb + it*4096 + t*8, db + it*4096 + wvb*8);
    bf8_t ann = *(const bf8_t*)(arow + ksn*32);
    asm volatile("s_waitcnt vmcnt(6)" ::: "memory");
    __builtin_amdgcn_sched_barrier(0);
    __builtin_amdgcn_s_barrier();
    __builtin_amdgcn_sched_barrier(0);
    const unsigned short* bb = &Bs[ks&3][0] + g*2048;
    __builtin_amdgcn_s_setprio(1);
    #pragma unroll
    for (int ct=0; ct<16; ct++){
      bf8_t b = *(const bf8_t*)(bb + (ct*16 + li)*8);
      acc[ct] = mfma16(ac, b, acc[ct]);
    }
    __builtin_amdgcn_s_setprio(0);
    ac = an; an = ann;
  }
  #pragma unroll
  for (int ct=0; ct<16; ct++){
    int c = ct*16 + li;
    float bv = b2[c];
    #pragma unroll
    for (int j=0;j<4;j++)
      emb[((size_t)m*NTOT + n0 + w*16 + 4*g + j)*256 + c] = f2bf(acc[ct][j] + bv);
  }
}

// ---------- K4: scores -> p = exp((emb.Ws + bs)/16) ----------
__global__ __launch_bounds__(256) void k_scores(const unsigned short* __restrict__ emb,
    const float* __restrict__ Wsm, const float* __restrict__ bsv, float* __restrict__ p){
  const int m = blockIdx.y;
  const int n = blockIdx.x*256 + threadIdx.x;
  __shared__ float Wss[1024];
  ((float4*)Wss)[threadIdx.x] = ((const float4*)Wsm)[threadIdx.x];
  __syncthreads();
  const u16x8* er = (const u16x8*)(emb + ((size_t)m*NTOT + n)*256);
  float a0=0.f,a1=0.f,a2=0.f,a3=0.f;
  for (int d8=0; d8<32; d8++){
    u16x8 e = er[d8];
    #pragma unroll
    for (int i=0;i<8;i++){
      float ev = bf2f(e[i]);
      const float* wv = &Wss[(d8*8+i)*4];
      a0 += ev*wv[0]; a1 += ev*wv[1]; a2 += ev*wv[2]; a3 += ev*wv[3];
    }
  }
  float4 o;
  o.x = expf((a0 + bsv[0]) * 0.0625f);
  o.y = expf((a1 + bsv[1]) * 0.0625f);
  o.z = expf((a2 + bsv[2]) * 0.0625f);
  o.w = expf((a3 + bsv[3]) * 0.0625f);
  ((float4*)p)[(size_t)m*NTOT + n] = o;
}

// ---------- K5: bag start offsets ----------
__global__ void k_starts(const int* __restrict__ idx, int* __restrict__ starts){
  int t = threadIdx.x;
  if (t <= NBAG){
    int lo = 0, hi = NTOT;
    while (lo < hi){ int mid = (lo + hi) >> 1; if (idx[mid] < t) lo = mid + 1; else hi = mid; }
    starts[t] = lo;
  }
}

// ---------- K6: en = relu(emb @ Wmf + bm) -> bf16 ----------
__global__ __launch_bounds__(256) void k_embnew(const unsigned short* __restrict__ emb,
    const unsigned short* __restrict__ Wmf, const float* __restrict__ bm,
    unsigned short* __restrict__ en){
  const int m = blockIdx.y, n0 = blockIdx.x*64;
  const int t = threadIdx.x, w = t>>6, l = t&63;
  const int g = l>>4, li = l&15;
  const int wvb = (t & ~63);
  __shared__ unsigned short Bs[32768];   // full Wmf [32][128][8] = 64KB
  #pragma unroll
  for (int it=0; it<16; it++)
    GLD16(Wmf + it*2048 + t*8, Bs + it*2048 + wvb*8);
  asm volatile("s_waitcnt vmcnt(0)" ::: "memory");
  __syncthreads();
  f32x4 acc[8];
  const f32x4 z4 = {0.f,0.f,0.f,0.f};
  #pragma unroll
  for (int ct=0;ct<8;ct++) acc[ct] = z4;
  const unsigned short* arow = emb + ((size_t)m*NTOT + n0 + w*16 + li)*256 + g*8;
  #pragma unroll
  for (int ks=0; ks<8; ks++){
    bf8_t a = *(const bf8_t*)(arow + ks*32);
    #pragma unroll
    for (int ct=0; ct<8; ct++){
      bf8_t b = *(const bf8_t*)(Bs + (ks*4+g)*1024 + (ct*16 + li)*8);
      acc[ct] = mfma16(a, b, acc[ct]);
    }
  }
  #pragma unroll
  for (int ct=0; ct<8; ct++){
    int c = ct*16 + li;
    float bv = bm[c];
    #pragma unroll
    for (int j=0;j<4;j++)
      en[((size_t)m*NTOT + n0 + w*16 + 4*g + j)*128 + c] = f2bf(fmaxf(acc[ct][j] + bv, 0.f));
  }
}

// ---------- K7: per (bag,m): seg = sum p; out[e] = sum_n en * p[k]/seg[k] ----------
__global__ __launch_bounds__(256) void k_pool(const unsigned short* __restrict__ en,
    const float* __restrict__ p, const int* __restrict__ starts, float* __restrict__ out){
  const int b = blockIdx.x, m = blockIdx.y;
  const int t = threadIdx.x;
  const int s0 = starts[b], s1 = starts[b+1];
  float sp0=0.f,sp1=0.f,sp2=0.f,sp3=0.f;
  for (int n = s0 + t; n < s1; n += 256){
    float4 pv = ((const float4*)p)[(size_t)m*NTOT + n];
    sp0 += pv.x; sp1 += pv.y; sp2 += pv.z; sp3 += pv.w;
  }
  #pragma unroll
  for (int off=1; off<64; off<<=1){
    sp0 += __shfl_xor(sp0, off); sp1 += __shfl_xor(sp1, off);
    sp2 += __shfl_xor(sp2, off); sp3 += __shfl_xor(sp3, off);
  }
  __shared__ float wred[4][4];
  __shared__ float winv[4];
  if ((t & 63) == 0){ wred[t>>6][0]=sp0; wred[t>>6][1]=sp1; wred[t>>6][2]=sp2; wred[t>>6][3]=sp3; }
  __syncthreads();
  if (t < 4){
    float s = wred[0][t] + wred[1][t] + wred[2][t] + wred[3][t];
    winv[t] = (s > 0.f) ? 1.0f / s : 0.f;
  }
  __syncthreads();
  const int e = t & 127, half = t >> 7;
  const int k = e >> 5;
  float accv = 0.f;
  for (int n = s0 + half; n < s1; n += 2){
    float wq = p[((size_t)m*NTOT + n)*4 + k];
    float v = bf2f(en[((size_t)m*NTOT + n)*128 + e]);
    accv = fmaf(v, wq, accv);
  }
  accv *= winv[k];
  __shared__ float ac2[2][128];
  ac2[half][e] = accv;
  __syncthreads();
  if (t < 128) out[((size_t)b*NMC + m)*128 + t] = ac2[0][t] + ac2[1][t];
}

extern "C" void kernel_launch(void* const* d_in, const int* in_sizes, int n_in,
                              void* d_out, int out_size, void* d_ws, size_t ws_size,
                              hipStream_t stream) {
  const float* X    = (const float*)d_in[0];
  const int*   Xidx = (const int*)  d_in[1];
  const float* Om1  = (const float*)d_in[2];
  const float* Om2  = (const float*)d_in[3];
  const float* W1   = (const float*)d_in[4];
  const float* b1   = (const float*)d_in[5];
  const float* W2   = (const float*)d_in[6];
  const float* b2   = (const float*)d_in[7];
  const float* Wsm  = (const float*)d_in[8];
  const float* bsv  = (const float*)d_in[9];
  const float* Wm   = (const float*)d_in[10];
  const float* bm   = (const float*)d_in[11];
  float* out = (float*)d_out;

  // ws aliasing (lifetimes are strictly sequential):
  //   [0,128M)    phi  [alive k_phi1..k_emb]; then en/p/starts overlay it
  //   [128M,192M) h    [k_phi2a..k_phi2b]; Xb (before) and emb (after) overlay it
  //   [192M,..)   packed weights (alive whole run)
  char* ws = (char*)d_ws;
  unsigned short* phi  = (unsigned short*)(ws);                    // 128MiB
  unsigned short* en   = (unsigned short*)(ws);                    // 16MiB (alias phi)
  float* p             = (float*)(ws + 16777216ull);               // 1MiB  (alias phi)
  int* starts          = (int*)(ws + 17825792ull);                 // 260B  (alias phi)
  unsigned short* h    = (unsigned short*)(ws + 134217728ull);     // 64MiB
  unsigned short* Xb   = (unsigned short*)(ws + 134217728ull);     // 32MiB (alias h)
  unsigned short* emb  = (unsigned short*)(ws + 134217728ull);     // 32MiB (alias h)
  unsigned short* Om1f = (unsigned short*)(ws + 201326592ull);     // 4MiB
  unsigned short* W1f  = (unsigned short*)(ws + 205520896ull);     // 1MiB
  unsigned short* Om2f = (unsigned short*)(ws + 206569472ull);     // 2MiB
  unsigned short* W2f  = (unsigned short*)(ws + 208666624ull);     // 0.5MiB
  unsigned short* Wmf  = (unsigned short*)(ws + 209190912ull);     // 64KiB

  k_cvt   <<<2048, 256, 0, stream>>>(X, Xb, NTOT*1024/8);
  k_pack8 <<<dim3(256,4), 256, 0, stream>>>(Om1, Om1f, 1024, 512);
  k_pack8 <<<dim3(256,1), 256, 0, stream>>>(W1,  W1f,  1024, 512);
  k_pack8 <<<dim3(128,4), 256, 0, stream>>>(Om2, Om2f, 512,  512);
  k_pack8 <<<dim3(128,1), 256, 0, stream>>>(W2,  W2f,  1024, 256);
  k_pack8 <<<dim3(16,1),  256, 0, stream>>>(Wm,  Wmf,  256,  128);
  k_phi1  <<<dim3(128,4), 512, 0, stream>>>(Xb, Om1f, phi);
  k_phi2a <<<dim3(128,4), 512, 0, stream>>>(phi, W1f, b1, h);
  k_phi2b <<<dim3(128,4), 512, 0, stream>>>(h, Om2f, phi);
  k_emb   <<<dim3(128,4), 512, 0, stream>>>(phi, W2f, b2, emb);
  k_scores<<<dim3(64,4),  256, 0, stream>>>(emb, Wsm, bsv, p);
  k_embnew<<<dim3(256,4), 256, 0, stream>>>(emb, Wmf, bm, en);
  k_starts<<<1, 128, 0, stream>>>(Xidx, starts);
  k_pool  <<<dim3(64,4),  256, 0, stream>>>(en, p, starts, out);
}